// Round 15
// baseline (113.258 us; speedup 1.0000x reference)
//
#include <hip/hip_runtime.h>
#include <hip/hip_bf16.h>

typedef short bf16x8 __attribute__((ext_vector_type(8)));
typedef short bf16x4 __attribute__((ext_vector_type(4)));
typedef float f32x4 __attribute__((ext_vector_type(4)));
typedef unsigned short ushort8v __attribute__((ext_vector_type(8)));

#define TPB  512
#define NWIN 8            // windows per persistent block; grid = 4096/NWIN = 512 = 2/CU exactly

// LGKM-only barrier: __syncthreads drains vmcnt(0) too (m97 asm), which would
// force the cross-window prefetch loads + output stores to retire at the barrier.
// All in-loop hazards here are LDS-only, so lgkmcnt(0)+s_barrier suffices.
// sched_barrier(0) fences compiler reordering across the asm (rule-18).
#define BAR_LGKM() do {                                              \
    asm volatile("s_waitcnt lgkmcnt(0)\n\ts_barrier" ::: "memory");  \
    __builtin_amdgcn_sched_barrier(0);                               \
  } while (0)

// HW bf16 convert (RNE) — compiler emits v_cvt_pk_bf16_f32; do NOT hand-roll (r7/r8 lesson).
__device__ __forceinline__ unsigned short f2bf(float f) {
  __hip_bfloat16 h = __float2bfloat16(f);
  return __builtin_bit_cast(unsigned short, h);
}

__device__ __forceinline__ bf16x4 pack4(float a, float b, float c, float d) {
  bf16x4 v;
  v[0] = (short)f2bf(a); v[1] = (short)f2bf(b);
  v[2] = (short)f2bf(c); v[3] = (short)f2bf(d);
  return v;
}

// K=16 bf16 MFMA. A-frag k-pattern (k=4g+j) == D-layout row pattern (row=4g+r),
// so D-fragments feed K=16 MFMAs directly; with B = c*Identity it TRANSPOSES a
// 16x16 block in the matrix pipe (D = c*X^T).
__device__ __forceinline__ f32x4 mfma16(bf16x4 a, bf16x4 b, f32x4 c) {
#if __has_builtin(__builtin_amdgcn_mfma_f32_16x16x16_bf16)
  return __builtin_amdgcn_mfma_f32_16x16x16_bf16(a, b, c, 0, 0, 0);
#elif __has_builtin(__builtin_amdgcn_mfma_f32_16x16x16bf16_1k)
  return __builtin_amdgcn_mfma_f32_16x16x16bf16_1k(a, b, c, 0, 0, 0);
#else
  f32x4 d;
  asm("v_mfma_f32_16x16x16_bf16 %0, %1, %2, %3" : "=v"(d) : "v"(a), "v"(b), "v"(c));
  return d;
#endif
}

// raw v_exp_f32 / v_rcp_f32 — skip ocml edge-case wrappers (r12/r13: real VALU win)
__device__ __forceinline__ float exp2_raw(float x) {
#if __has_builtin(__builtin_amdgcn_exp2f)
  return __builtin_amdgcn_exp2f(x);
#else
  float r; asm("v_exp_f32 %0, %1" : "=v"(r) : "v"(x)); return r;
#endif
}
__device__ __forceinline__ float rcp_raw(float x) {
#if __has_builtin(__builtin_amdgcn_rcpf)
  return __builtin_amdgcn_rcpf(x);
#else
  float r; asm("v_rcp_f32 %0, %1" : "=v"(r) : "v"(x)); return r;
#endif
}

// LDS map (ushort elems). Persistent-loop overlays:
//   [0..8192)      sWin (staging, overlays dead Q of previous iteration)
//   [0..10240)     Q    (QKV phase -> bq regs)
//   [10240..20480) K    (QKV phase -> ak regs)
//   [10240..18432) ATT  (overlays dead K — frees the stage-write slot)
//   [20480..29696) VT
#define Q_OFF   0
#define K_OFF   10240
#define ATT_OFF 10240
#define VT_OFF  20480
#define SMEM_ELEMS 29696 // 59,392 B -> 2 blocks/CU (118,784 <= 131,072 usable)

// scale * log2(e): softmax in log2 domain; logits tiny -> no max-subtraction needed.
#define CQ 0.25501817f   // (1/sqrt(32)) * 1.4426950408889634

__global__ void prep_weights(const float* __restrict__ wqkv,
                             const float* __restrict__ wproj,
                             unsigned short* __restrict__ wt) {
  int idx = blockIdx.x * 256 + threadIdx.x;
  if (idx < 384 * 128) {                 // wqkvT[n][k] = bf16(wqkv[k][n])
    int n = idx >> 7, k = idx & 127;
    wt[idx] = f2bf(wqkv[k * 384 + n]);
  } else if (idx < 384 * 128 + 128 * 128) { // wprojT[c][k] = bf16(wproj[k][c])
    int j = idx - 384 * 128;
    int c = j >> 7, k = j & 127;
    wt[idx] = f2bf(wproj[k * 128 + c]);
  }
}

__device__ __forceinline__ size_t winbase_of(int wid) {
  int b = wid >> 8, wh = (wid >> 4) & 15, ww = wid & 15;
  return (((size_t)b * 112 + wh * 7) * 112 + ww * 7) * 128;
}

__launch_bounds__(TPB, 2)
__global__ void win_attn(const float* __restrict__ x,
                         const float* __restrict__ bqkv,
                         const float* __restrict__ bproj,
                         const unsigned short* __restrict__ wt,
                         float* __restrict__ out) {
  __shared__ __align__(16) unsigned short smem[SMEM_ELEMS];
  const int tid  = threadIdx.x;
  const int wave = tid >> 6;
  const int lane = tid & 63;
  const int g    = lane >> 4;   // 16-lane group id (0..3)
  const int l15  = lane & 15;

  const unsigned short* wqkvT  = wt;               // [384][128] bf16
  const unsigned short* wprojT = wt + 384 * 128;   // [128][128] bf16

  // identity B-frags for the transpose-mfma: B[k=4g+j][col=l15] = c * delta(4g+j, l15)
  bf16x4 idQ = {0, 0, 0, 0}, idK = {0, 0, 0, 0};
  if ((l15 >> 2) == g) {
    idQ[l15 & 3] = (short)f2bf(CQ);       // Q gets scale*log2e folded in
    idK[l15 & 3] = (short)0x3F80;         // 1.0 bf16
  }

  // staging geometry (invariant): thread covers rows row0 and row0+32; rows>48 clamp
  // to row 48 (finite garbage safe: K toks masked, V toks killed by P=0, Q rows unused).
  // (row+32)&7 == row&7, so both chunks share the same XOR granule.
  const int row0  = tid >> 4, c8 = tid & 15;
  const int rowc0 = min(row0, 48), rowc1 = min(row0 + 32, 48);
  const int xo0   = ((rowc0 / 7) * 112 + (rowc0 % 7)) * 128 + c8 * 8;
  const int xo1   = ((rowc1 / 7) * 112 + (rowc1 % 7)) * 128 + c8 * 8;
  const int sw    = (c8 * 8) ^ ((row0 & 7) << 3);
  const int dst0  = row0 * 128 + sw;
  const int dst1  = (row0 + 32) * 128 + sw;

  const f32x4 zero4 = {0.f, 0.f, 0.f, 0.f};
  const int h    = wave >> 1;
  const int half = wave & 1;
  const int ccol = wave * 16 + l15;

  // ---------- prologue: stage window 0 ----------
  float4 pfa, pfb, pfc, pfd;
  {
    size_t wb0 = winbase_of((int)blockIdx.x);   // w=0: wid = blockIdx.x
    const float4* s0 = (const float4*)(x + wb0 + xo0);
    const float4* s1 = (const float4*)(x + wb0 + xo1);
    pfa = s0[0]; pfb = s0[1]; pfc = s1[0]; pfd = s1[1];
  }
  {
    ushort8v v8;
    v8[0]=f2bf(pfa.x); v8[1]=f2bf(pfa.y); v8[2]=f2bf(pfa.z); v8[3]=f2bf(pfa.w);
    v8[4]=f2bf(pfb.x); v8[5]=f2bf(pfb.y); v8[6]=f2bf(pfb.z); v8[7]=f2bf(pfb.w);
    *(ushort8v*)(&smem[dst0]) = v8;
    v8[0]=f2bf(pfc.x); v8[1]=f2bf(pfc.y); v8[2]=f2bf(pfc.z); v8[3]=f2bf(pfc.w);
    v8[4]=f2bf(pfd.x); v8[5]=f2bf(pfd.y); v8[6]=f2bf(pfd.z); v8[7]=f2bf(pfd.w);
    *(ushort8v*)(&smem[dst1]) = v8;
  }
  __syncthreads();   // S0 (once; full sync is fine here)

  for (int w = 0; w < NWIN; w++) {
    const int wid = w * 512 + (int)blockIdx.x;
    const size_t winbase = winbase_of(wid);

    // ---------- af loads (sWin -> regs) ----------
    bf16x8 af[4][4];
#pragma unroll
    for (int mt = 0; mt < 4; mt++)
#pragma unroll
      for (int kt = 0; kt < 4; kt++) {
        int row = mt * 16 + l15;
        int colE = kt * 32 + g * 8;
        af[mt][kt] = *(const bf16x8*)(&smem[row * 128 + (colE ^ ((row & 7) << 3))]);
      }
    BAR_LGKM();   // S1: af + prev proj ATT-reads done (LDS-only hazard)

    // ---------- phase 1: QKV = win @ w_qkv + b_qkv ----------
#pragma unroll
    for (int i = 0; i < 3; i++) {
      int nt = wave * 3 + i;          // 0..23 (n-tile of 384)
      int n  = nt * 16 + l15;
      float bias = bqkv[n];
      f32x4 binit = {bias, bias, bias, bias};

      bf16x8 bw[4];
#pragma unroll
      for (int kt = 0; kt < 4; kt++)
        bw[kt] = *(const bf16x8*)(wqkvT + n * 128 + kt * 32 + g * 8);

      f32x4 acc[4] = {binit, binit, binit, binit};
      __builtin_amdgcn_s_setprio(1);
#pragma unroll
      for (int kt = 0; kt < 4; kt++)
#pragma unroll
        for (int mt = 0; mt < 4; mt++)
          acc[mt] = __builtin_amdgcn_mfma_f32_16x16x32_bf16(af[mt][kt], bw[kt], acc[mt], 0, 0, 0);
      __builtin_amdgcn_s_setprio(0);

      int sec = nt >> 3;       // 0=Q 1=K 2=V (uniform per (wave,i))
      if (sec == 2) {
        int hn = n & 127, hh = hn >> 5, d = hn & 31;
#pragma unroll
        for (int mt = 0; mt < 4; mt++) {
          bf16x4 pv = pack4(acc[mt][0], acc[mt][1], acc[mt][2], acc[mt][3]);
          *(bf16x4*)(&smem[VT_OFF + hh * 2304 + d * 72 + mt * 16 + g * 4]) = pv;
        }
      } else {
        int t7 = nt & 7;
        int hh = t7 >> 1, d0 = (t7 & 1) * 16;
        const bf16x4 idf = (sec == 0) ? idQ : idK;
        const int base = (sec == 0 ? Q_OFF : K_OFF) + hh * 2560 + d0 + g * 4;
#pragma unroll
        for (int mt = 0; mt < 4; mt++) {
          bf16x4 ax = pack4(acc[mt][0], acc[mt][1], acc[mt][2], acc[mt][3]);
          f32x4 dt = mfma16(ax, idf, zero4);
          bf16x4 wv = pack4(dt[0], dt[1], dt[2], dt[3]);
          *(bf16x4*)(&smem[base + (mt * 16 + l15) * 40]) = wv;
        }
      }
    }
    BAR_LGKM();   // S2: Q/K/VT visible (LDS-only hazard)

    // ---------- phase 2: attention, swapped QK^T ----------
    bf16x8 ak[4];
#pragma unroll
    for (int kt = 0; kt < 4; kt++) {
      int row = kt * 16 + l15;
      ak[kt] = *(const bf16x8*)(&smem[K_OFF + h * 2560 + row * 40 + g * 8]);
    }
    bf16x8 bq[2];
#pragma unroll
    for (int qt = 0; qt < 2; qt++) {
      int row = half * 32 + qt * 16 + l15;
      bq[qt] = *(const bf16x8*)(&smem[Q_OFF + h * 2560 + row * 40 + g * 8]);
    }
    bf16x4 bv16[2][4];
#pragma unroll
    for (int nt2 = 0; nt2 < 2; nt2++)
#pragma unroll
      for (int kt = 0; kt < 4; kt++)
        bv16[nt2][kt] = *(const bf16x4*)(&smem[VT_OFF + h * 2304 + (nt2 * 16 + l15) * 72 + kt * 16 + g * 4]);

    f32x4 s[4][2];
    __builtin_amdgcn_s_setprio(1);
#pragma unroll
    for (int kt = 0; kt < 4; kt++)
#pragma unroll
      for (int qt = 0; qt < 2; qt++)
        s[kt][qt] = __builtin_amdgcn_mfma_f32_16x16x32_bf16(ak[kt], bq[qt], zero4, 0, 0, 0);
    __builtin_amdgcn_s_setprio(0);

    // softmax (no max-subtraction; only tok 48 of kt=3 is valid)
    bf16x4 ap16[2][4];
    const bool v48 = (g == 0);
#pragma unroll
    for (int qt = 0; qt < 2; qt++) {
      float sum = 0.f;
#pragma unroll
      for (int kt = 0; kt < 3; kt++)
#pragma unroll
        for (int r = 0; r < 4; r++) {
          float p = exp2_raw(s[kt][qt][r]);
          s[kt][qt][r] = p;
          sum += p;
        }
      float p3 = v48 ? exp2_raw(s[3][qt][0]) : 0.0f;
      sum += p3;
      sum += __shfl_xor(sum, 16);
      sum += __shfl_xor(sum, 32);
      float inv = rcp_raw(sum);
#pragma unroll
      for (int kt = 0; kt < 3; kt++)
        ap16[qt][kt] = pack4(s[kt][qt][0] * inv, s[kt][qt][1] * inv,
                             s[kt][qt][2] * inv, s[kt][qt][3] * inv);
      ap16[qt][3] = pack4(p3 * inv, 0.f, 0.f, 0.f);
    }

    // PV straight from registers
    f32x4 o[2][2] = {{zero4, zero4}, {zero4, zero4}};
    __builtin_amdgcn_s_setprio(1);
#pragma unroll
    for (int kt = 0; kt < 4; kt++)
#pragma unroll
      for (int m2 = 0; m2 < 2; m2++)
#pragma unroll
        for (int nt2 = 0; nt2 < 2; nt2++)
          o[m2][nt2] = mfma16(ap16[m2][kt], bv16[nt2][kt], o[m2][nt2]);
    __builtin_amdgcn_s_setprio(0);

    // transpose O tiles in the matrix pipe (reg-only)
    bf16x4 attw[2][2];
#pragma unroll
    for (int m2 = 0; m2 < 2; m2++)
#pragma unroll
      for (int nt2 = 0; nt2 < 2; nt2++) {
        bf16x4 ox = pack4(o[m2][nt2][0], o[m2][nt2][1], o[m2][nt2][2], o[m2][nt2][3]);
        f32x4 ot = mfma16(ox, idK, zero4);
        attw[m2][nt2] = pack4(ot[0], ot[1], ot[2], ot[3]);
      }

    // T14: issue next window's staging loads NOW — with the lgkm-only S3 they
    // actually stay in flight until the cvt+ds_write after S3.
    if (w < NWIN - 1) {
      size_t wbn = winbase_of(wid + 512);
      const float4* s0 = (const float4*)(x + wbn + xo0);
      const float4* s1 = (const float4*)(x + wbn + xo1);
      pfa = s0[0]; pfb = s0[1]; pfc = s1[0]; pfd = s1[1];
    }

    // proj weights (L2-resident, independent of LDS)
    bf16x8 bwp[4];
#pragma unroll
    for (int kt = 0; kt < 4; kt++)
      bwp[kt] = *(const bf16x8*)(wprojT + ccol * 128 + kt * 32 + g * 8);
    float biasp = bproj[ccol];

    BAR_LGKM();   // S3: Q/K/VT reads done; ATT (over K) + sWin (over Q) writable

#pragma unroll
    for (int m2 = 0; m2 < 2; m2++)
#pragma unroll
      for (int nt2 = 0; nt2 < 2; nt2++) {
        int tok  = (half * 2 + m2) * 16 + l15;
        int col0 = h * 32 + nt2 * 16 + g * 4;
        *(bf16x4*)(&smem[ATT_OFF + tok * 128 + (col0 ^ ((tok & 7) << 3))]) = attw[m2][nt2];
      }
    if (w < NWIN - 1) {
      ushort8v v8;
      v8[0]=f2bf(pfa.x); v8[1]=f2bf(pfa.y); v8[2]=f2bf(pfa.z); v8[3]=f2bf(pfa.w);
      v8[4]=f2bf(pfb.x); v8[5]=f2bf(pfb.y); v8[6]=f2bf(pfb.z); v8[7]=f2bf(pfb.w);
      *(ushort8v*)(&smem[dst0]) = v8;
      v8[0]=f2bf(pfc.x); v8[1]=f2bf(pfc.y); v8[2]=f2bf(pfc.z); v8[3]=f2bf(pfc.w);
      v8[4]=f2bf(pfd.x); v8[5]=f2bf(pfd.y); v8[6]=f2bf(pfd.z); v8[7]=f2bf(pfd.w);
      *(ushort8v*)(&smem[dst1]) = v8;
    }
    BAR_LGKM();   // S4: ATT + next sWin visible (LDS-only hazard)

    // ---------- proj + bias + store (fp32 out) ----------
    f32x4 po[4] = {zero4, zero4, zero4, zero4};
    __builtin_amdgcn_s_setprio(1);
#pragma unroll
    for (int kt = 0; kt < 4; kt++) {
#pragma unroll
      for (int mt = 0; mt < 4; mt++) {
        int row = mt * 16 + l15;
        int colE = kt * 32 + g * 8;
        bf16x8 aa = *(const bf16x8*)(&smem[ATT_OFF + row * 128 + (colE ^ ((row & 7) << 3))]);
        po[mt] = __builtin_amdgcn_mfma_f32_16x16x32_bf16(aa, bwp[kt], po[mt], 0, 0, 0);
      }
    }
    __builtin_amdgcn_s_setprio(0);
#pragma unroll
    for (int mt = 0; mt < 3; mt++)
#pragma unroll
      for (int r = 0; r < 4; r++) {
        int tok = mt * 16 + g * 4 + r;
        size_t off = winbase + ((size_t)(tok / 7) * 112 + (tok % 7)) * 128 + ccol;
        out[off] = po[mt][r] + biasp;
      }
    if (g == 0) {
      size_t off = winbase + ((size_t)6 * 112 + 6) * 128 + ccol;   // tok 48 = (6,6)
      out[off] = po[3][0] + biasp;
    }
  }
}

extern "C" void kernel_launch(void* const* d_in, const int* in_sizes, int n_in,
                              void* d_out, int out_size, void* d_ws, size_t ws_size,
                              hipStream_t stream) {
  (void)in_sizes; (void)n_in; (void)out_size; (void)ws_size;
  const float* x     = (const float*)d_in[0];
  const float* wqkv  = (const float*)d_in[1];
  const float* bqkv  = (const float*)d_in[2];
  const float* wproj = (const float*)d_in[3];
  const float* bproj = (const float*)d_in[4];
  unsigned short* wt = (unsigned short*)d_ws;   // 131072 B: wqkvT + wprojT (bf16)

  hipLaunchKernelGGL(prep_weights, dim3(256), dim3(256), 0, stream, wqkv, wproj, wt);
  hipLaunchKernelGGL(win_attn, dim3(4096 / NWIN), dim3(TPB), 0, stream,
                     x, bqkv, bproj, wt, (float*)d_out);
}

// Round 16
// 85.434 us; speedup vs baseline: 1.3257x; 1.3257x over previous
//
#include <hip/hip_runtime.h>
#include <hip/hip_bf16.h>

typedef short bf16x8 __attribute__((ext_vector_type(8)));
typedef short bf16x4 __attribute__((ext_vector_type(4)));
typedef float f32x4 __attribute__((ext_vector_type(4)));
typedef unsigned short ushort8v __attribute__((ext_vector_type(8)));

#define TPB  512
#define NWIN 8            // windows per persistent block; grid = 4096/NWIN = 512 = 2/CU exactly

// r15 lesson (== guide m141): lgkm-only barrier asm + sched_barrier(0) pinned the
// scheduler, VGPR 124->96, dur +37%. __syncthreads()'s vmcnt drain is cheaper than
// losing compiler scheduling freedom. Keep plain __syncthreads().

// HW bf16 convert (RNE) — compiler emits v_cvt_pk_bf16_f32; do NOT hand-roll (r7/r8 lesson).
__device__ __forceinline__ unsigned short f2bf(float f) {
  __hip_bfloat16 h = __float2bfloat16(f);
  return __builtin_bit_cast(unsigned short, h);
}

__device__ __forceinline__ bf16x4 pack4(float a, float b, float c, float d) {
  bf16x4 v;
  v[0] = (short)f2bf(a); v[1] = (short)f2bf(b);
  v[2] = (short)f2bf(c); v[3] = (short)f2bf(d);
  return v;
}

// K=16 bf16 MFMA. A-frag k-pattern (k=4g+j) == D-layout row pattern (row=4g+r),
// so D-fragments feed K=16 MFMAs directly; with B = c*Identity it TRANSPOSES a
// 16x16 block in the matrix pipe (D = c*X^T).
__device__ __forceinline__ f32x4 mfma16(bf16x4 a, bf16x4 b, f32x4 c) {
#if __has_builtin(__builtin_amdgcn_mfma_f32_16x16x16_bf16)
  return __builtin_amdgcn_mfma_f32_16x16x16_bf16(a, b, c, 0, 0, 0);
#elif __has_builtin(__builtin_amdgcn_mfma_f32_16x16x16bf16_1k)
  return __builtin_amdgcn_mfma_f32_16x16x16bf16_1k(a, b, c, 0, 0, 0);
#else
  f32x4 d;
  asm("v_mfma_f32_16x16x16_bf16 %0, %1, %2, %3" : "=v"(d) : "v"(a), "v"(b), "v"(c));
  return d;
#endif
}

// raw v_exp_f32 / v_rcp_f32 — skip ocml edge-case wrappers (r12/r13: real VALU win)
__device__ __forceinline__ float exp2_raw(float x) {
#if __has_builtin(__builtin_amdgcn_exp2f)
  return __builtin_amdgcn_exp2f(x);
#else
  float r; asm("v_exp_f32 %0, %1" : "=v"(r) : "v"(x)); return r;
#endif
}
__device__ __forceinline__ float rcp_raw(float x) {
#if __has_builtin(__builtin_amdgcn_rcpf)
  return __builtin_amdgcn_rcpf(x);
#else
  float r; asm("v_rcp_f32 %0, %1" : "=v"(r) : "v"(x)); return r;
#endif
}

// LDS map (ushort elems). Persistent-loop overlays (r14):
//   [0..8192)      sWin (staging, overlays dead Q of previous iteration)
//   [0..10240)     Q    (QKV phase -> bq regs)
//   [10240..20480) K    (QKV phase -> ak regs)
//   [10240..18432) ATT  (overlays dead K — this is what frees the stage-write slot)
//   [20480..29696) VT
#define Q_OFF   0
#define K_OFF   10240
#define ATT_OFF 10240
#define VT_OFF  20480
#define SMEM_ELEMS 29696 // 59,392 B -> 2 blocks/CU (118,784 <= 131,072 usable)

// scale * log2(e): softmax in log2 domain; logits tiny -> no max-subtraction needed.
#define CQ 0.25501817f   // (1/sqrt(32)) * 1.4426950408889634

__global__ void prep_weights(const float* __restrict__ wqkv,
                             const float* __restrict__ wproj,
                             unsigned short* __restrict__ wt) {
  int idx = blockIdx.x * 256 + threadIdx.x;
  if (idx < 384 * 128) {                 // wqkvT[n][k] = bf16(wqkv[k][n])
    int n = idx >> 7, k = idx & 127;
    wt[idx] = f2bf(wqkv[k * 384 + n]);
  } else if (idx < 384 * 128 + 128 * 128) { // wprojT[c][k] = bf16(wproj[k][c])
    int j = idx - 384 * 128;
    int c = j >> 7, k = j & 127;
    wt[idx] = f2bf(wproj[k * 128 + c]);
  }
}

__device__ __forceinline__ size_t winbase_of(int wid) {
  int b = wid >> 8, wh = (wid >> 4) & 15, ww = wid & 15;
  return (((size_t)b * 112 + wh * 7) * 112 + ww * 7) * 128;
}

__launch_bounds__(TPB, 2)   // cap 128 VGPR; residency is LDS-pinned at 2 blocks/CU anyway
__global__ void win_attn(const float* __restrict__ x,
                         const float* __restrict__ bqkv,
                         const float* __restrict__ bproj,
                         const unsigned short* __restrict__ wt,
                         float* __restrict__ out) {
  __shared__ __align__(16) unsigned short smem[SMEM_ELEMS];
  const int tid  = threadIdx.x;
  const int wave = tid >> 6;
  const int lane = tid & 63;
  const int g    = lane >> 4;   // 16-lane group id (0..3)
  const int l15  = lane & 15;

  const unsigned short* wqkvT  = wt;               // [384][128] bf16
  const unsigned short* wprojT = wt + 384 * 128;   // [128][128] bf16

  // identity B-frags for the transpose-mfma: B[k=4g+j][col=l15] = c * delta(4g+j, l15)
  bf16x4 idQ = {0, 0, 0, 0}, idK = {0, 0, 0, 0};
  if ((l15 >> 2) == g) {
    idQ[l15 & 3] = (short)f2bf(CQ);       // Q gets scale*log2e folded in
    idK[l15 & 3] = (short)0x3F80;         // 1.0 bf16
  }

  // staging geometry (invariant): thread covers rows row0 and row0+32; rows>48 clamp
  // to row 48 (finite garbage safe: K toks masked, V toks killed by P=0, Q rows unused).
  // (row+32)&7 == row&7, so both chunks share the same XOR granule.
  const int row0  = tid >> 4, c8 = tid & 15;
  const int rowc0 = min(row0, 48), rowc1 = min(row0 + 32, 48);
  const int xo0   = ((rowc0 / 7) * 112 + (rowc0 % 7)) * 128 + c8 * 8;
  const int xo1   = ((rowc1 / 7) * 112 + (rowc1 % 7)) * 128 + c8 * 8;
  const int sw    = (c8 * 8) ^ ((row0 & 7) << 3);
  const int dst0  = row0 * 128 + sw;
  const int dst1  = (row0 + 32) * 128 + sw;

  const f32x4 zero4 = {0.f, 0.f, 0.f, 0.f};
  const int h    = wave >> 1;
  const int half = wave & 1;
  const int ccol = wave * 16 + l15;

  // ---------- prologue: stage window 0 ----------
  float4 pfa, pfb, pfc, pfd;
  {
    size_t wb0 = winbase_of((int)blockIdx.x);   // w=0: wid = blockIdx.x
    const float4* s0 = (const float4*)(x + wb0 + xo0);
    const float4* s1 = (const float4*)(x + wb0 + xo1);
    pfa = s0[0]; pfb = s0[1]; pfc = s1[0]; pfd = s1[1];
  }
  {
    ushort8v v8;
    v8[0]=f2bf(pfa.x); v8[1]=f2bf(pfa.y); v8[2]=f2bf(pfa.z); v8[3]=f2bf(pfa.w);
    v8[4]=f2bf(pfb.x); v8[5]=f2bf(pfb.y); v8[6]=f2bf(pfb.z); v8[7]=f2bf(pfb.w);
    *(ushort8v*)(&smem[dst0]) = v8;
    v8[0]=f2bf(pfc.x); v8[1]=f2bf(pfc.y); v8[2]=f2bf(pfc.z); v8[3]=f2bf(pfc.w);
    v8[4]=f2bf(pfd.x); v8[5]=f2bf(pfd.y); v8[6]=f2bf(pfd.z); v8[7]=f2bf(pfd.w);
    *(ushort8v*)(&smem[dst1]) = v8;
  }
  __syncthreads();   // S0: sWin(0) visible

  for (int w = 0; w < NWIN; w++) {
    const int wid = w * 512 + (int)blockIdx.x;
    const size_t winbase = winbase_of(wid);

    // ---------- af loads (sWin -> regs) ----------
    bf16x8 af[4][4];
#pragma unroll
    for (int mt = 0; mt < 4; mt++)
#pragma unroll
      for (int kt = 0; kt < 4; kt++) {
        int row = mt * 16 + l15;
        int colE = kt * 32 + g * 8;
        af[mt][kt] = *(const bf16x8*)(&smem[row * 128 + (colE ^ ((row & 7) << 3))]);
      }
    __syncthreads();   // S1: af (and prev-iter proj ATT reads) done; QKV writes safe

    // ---------- phase 1: QKV = win @ w_qkv + b_qkv ----------
#pragma unroll
    for (int i = 0; i < 3; i++) {
      int nt = wave * 3 + i;          // 0..23 (n-tile of 384)
      int n  = nt * 16 + l15;
      float bias = bqkv[n];
      f32x4 binit = {bias, bias, bias, bias};

      bf16x8 bw[4];
#pragma unroll
      for (int kt = 0; kt < 4; kt++)
        bw[kt] = *(const bf16x8*)(wqkvT + n * 128 + kt * 32 + g * 8);

      f32x4 acc[4] = {binit, binit, binit, binit};
      __builtin_amdgcn_s_setprio(1);
#pragma unroll
      for (int kt = 0; kt < 4; kt++)
#pragma unroll
        for (int mt = 0; mt < 4; mt++)
          acc[mt] = __builtin_amdgcn_mfma_f32_16x16x32_bf16(af[mt][kt], bw[kt], acc[mt], 0, 0, 0);
      __builtin_amdgcn_s_setprio(0);

      int sec = nt >> 3;       // 0=Q 1=K 2=V (uniform per (wave,i))
      if (sec == 2) {
        int hn = n & 127, hh = hn >> 5, d = hn & 31;
#pragma unroll
        for (int mt = 0; mt < 4; mt++) {
          bf16x4 pv = pack4(acc[mt][0], acc[mt][1], acc[mt][2], acc[mt][3]);
          *(bf16x4*)(&smem[VT_OFF + hh * 2304 + d * 72 + mt * 16 + g * 4]) = pv;
        }
      } else {
        int t7 = nt & 7;
        int hh = t7 >> 1, d0 = (t7 & 1) * 16;
        const bf16x4 idf = (sec == 0) ? idQ : idK;
        const int base = (sec == 0 ? Q_OFF : K_OFF) + hh * 2560 + d0 + g * 4;
#pragma unroll
        for (int mt = 0; mt < 4; mt++) {
          bf16x4 ax = pack4(acc[mt][0], acc[mt][1], acc[mt][2], acc[mt][3]);
          f32x4 dt = mfma16(ax, idf, zero4);
          bf16x4 wv = pack4(dt[0], dt[1], dt[2], dt[3]);
          *(bf16x4*)(&smem[base + (mt * 16 + l15) * 40]) = wv;
        }
      }
    }
    __syncthreads();   // S2: Q/K/VT visible

    // ---------- phase 2: attention, swapped QK^T ----------
    bf16x8 ak[4];
#pragma unroll
    for (int kt = 0; kt < 4; kt++) {
      int row = kt * 16 + l15;
      ak[kt] = *(const bf16x8*)(&smem[K_OFF + h * 2560 + row * 40 + g * 8]);
    }
    bf16x8 bq[2];
#pragma unroll
    for (int qt = 0; qt < 2; qt++) {
      int row = half * 32 + qt * 16 + l15;
      bq[qt] = *(const bf16x8*)(&smem[Q_OFF + h * 2560 + row * 40 + g * 8]);
    }
    bf16x4 bv16[2][4];
#pragma unroll
    for (int nt2 = 0; nt2 < 2; nt2++)
#pragma unroll
      for (int kt = 0; kt < 4; kt++)
        bv16[nt2][kt] = *(const bf16x4*)(&smem[VT_OFF + h * 2304 + (nt2 * 16 + l15) * 72 + kt * 16 + g * 4]);

    f32x4 s[4][2];
    __builtin_amdgcn_s_setprio(1);
#pragma unroll
    for (int kt = 0; kt < 4; kt++)
#pragma unroll
      for (int qt = 0; qt < 2; qt++)
        s[kt][qt] = __builtin_amdgcn_mfma_f32_16x16x32_bf16(ak[kt], bq[qt], zero4, 0, 0, 0);
    __builtin_amdgcn_s_setprio(0);

    // softmax (no max-subtraction; only tok 48 of kt=3 is valid)
    bf16x4 ap16[2][4];
    const bool v48 = (g == 0);
#pragma unroll
    for (int qt = 0; qt < 2; qt++) {
      float sum = 0.f;
#pragma unroll
      for (int kt = 0; kt < 3; kt++)
#pragma unroll
        for (int r = 0; r < 4; r++) {
          float p = exp2_raw(s[kt][qt][r]);
          s[kt][qt][r] = p;
          sum += p;
        }
      float p3 = v48 ? exp2_raw(s[3][qt][0]) : 0.0f;
      sum += p3;
      sum += __shfl_xor(sum, 16);
      sum += __shfl_xor(sum, 32);
      float inv = rcp_raw(sum);
#pragma unroll
      for (int kt = 0; kt < 3; kt++)
        ap16[qt][kt] = pack4(s[kt][qt][0] * inv, s[kt][qt][1] * inv,
                             s[kt][qt][2] * inv, s[kt][qt][3] * inv);
      ap16[qt][3] = pack4(p3 * inv, 0.f, 0.f, 0.f);
    }

    // PV straight from registers
    f32x4 o[2][2] = {{zero4, zero4}, {zero4, zero4}};
    __builtin_amdgcn_s_setprio(1);
#pragma unroll
    for (int kt = 0; kt < 4; kt++)
#pragma unroll
      for (int m2 = 0; m2 < 2; m2++)
#pragma unroll
        for (int nt2 = 0; nt2 < 2; nt2++)
          o[m2][nt2] = mfma16(ap16[m2][kt], bv16[nt2][kt], o[m2][nt2]);
    __builtin_amdgcn_s_setprio(0);

    // transpose O tiles in the matrix pipe (reg-only)
    bf16x4 attw[2][2];
#pragma unroll
    for (int m2 = 0; m2 < 2; m2++)
#pragma unroll
      for (int nt2 = 0; nt2 < 2; nt2++) {
        bf16x4 ox = pack4(o[m2][nt2][0], o[m2][nt2][1], o[m2][nt2][2], o[m2][nt2][3]);
        f32x4 ot = mfma16(ox, idK, zero4);
        attw[m2][nt2] = pack4(ot[0], ot[1], ot[2], ot[3]);
      }

    // T14: issue next window's staging loads NOW (consumed after S3) — latency
    // hides under the rest of attention + barriers + ATT writes.
    if (w < NWIN - 1) {
      size_t wbn = winbase_of(wid + 512);
      const float4* s0 = (const float4*)(x + wbn + xo0);
      const float4* s1 = (const float4*)(x + wbn + xo1);
      pfa = s0[0]; pfb = s0[1]; pfc = s1[0]; pfd = s1[1];
    }

    // proj weights (L2-resident, independent of LDS)
    bf16x8 bwp[4];
#pragma unroll
    for (int kt = 0; kt < 4; kt++)
      bwp[kt] = *(const bf16x8*)(wprojT + ccol * 128 + kt * 32 + g * 8);
    float biasp = bproj[ccol];

    __syncthreads();   // S3: all Q/K/VT reads done; ATT (over K) + sWin (over Q) writable

#pragma unroll
    for (int m2 = 0; m2 < 2; m2++)
#pragma unroll
      for (int nt2 = 0; nt2 < 2; nt2++) {
        int tok  = (half * 2 + m2) * 16 + l15;
        int col0 = h * 32 + nt2 * 16 + g * 4;
        *(bf16x4*)(&smem[ATT_OFF + tok * 128 + (col0 ^ ((tok & 7) << 3))]) = attw[m2][nt2];
      }
    if (w < NWIN - 1) {
      ushort8v v8;
      v8[0]=f2bf(pfa.x); v8[1]=f2bf(pfa.y); v8[2]=f2bf(pfa.z); v8[3]=f2bf(pfa.w);
      v8[4]=f2bf(pfb.x); v8[5]=f2bf(pfb.y); v8[6]=f2bf(pfb.z); v8[7]=f2bf(pfb.w);
      *(ushort8v*)(&smem[dst0]) = v8;
      v8[0]=f2bf(pfc.x); v8[1]=f2bf(pfc.y); v8[2]=f2bf(pfc.z); v8[3]=f2bf(pfc.w);
      v8[4]=f2bf(pfd.x); v8[5]=f2bf(pfd.y); v8[6]=f2bf(pfd.z); v8[7]=f2bf(pfd.w);
      *(ushort8v*)(&smem[dst1]) = v8;
    }
    __syncthreads();   // S4: ATT + next sWin visible

    // ---------- proj + bias + store (fp32 out) ----------
    f32x4 po[4] = {zero4, zero4, zero4, zero4};
    __builtin_amdgcn_s_setprio(1);
#pragma unroll
    for (int kt = 0; kt < 4; kt++) {
#pragma unroll
      for (int mt = 0; mt < 4; mt++) {
        int row = mt * 16 + l15;
        int colE = kt * 32 + g * 8;
        bf16x8 aa = *(const bf16x8*)(&smem[ATT_OFF + row * 128 + (colE ^ ((row & 7) << 3))]);
        po[mt] = __builtin_amdgcn_mfma_f32_16x16x32_bf16(aa, bwp[kt], po[mt], 0, 0, 0);
      }
    }
    __builtin_amdgcn_s_setprio(0);
#pragma unroll
    for (int mt = 0; mt < 3; mt++)
#pragma unroll
      for (int r = 0; r < 4; r++) {
        int tok = mt * 16 + g * 4 + r;
        size_t off = winbase + ((size_t)(tok / 7) * 112 + (tok % 7)) * 128 + ccol;
        out[off] = po[mt][r] + biasp;
      }
    if (g == 0) {
      size_t off = winbase + ((size_t)6 * 112 + 6) * 128 + ccol;   // tok 48 = (6,6)
      out[off] = po[3][0] + biasp;
    }
  }
}

extern "C" void kernel_launch(void* const* d_in, const int* in_sizes, int n_in,
                              void* d_out, int out_size, void* d_ws, size_t ws_size,
                              hipStream_t stream) {
  (void)in_sizes; (void)n_in; (void)out_size; (void)ws_size;
  const float* x     = (const float*)d_in[0];
  const float* wqkv  = (const float*)d_in[1];
  const float* bqkv  = (const float*)d_in[2];
  const float* wproj = (const float*)d_in[3];
  const float* bproj = (const float*)d_in[4];
  unsigned short* wt = (unsigned short*)d_ws;   // 131072 B: wqkvT + wprojT (bf16)

  hipLaunchKernelGGL(prep_weights, dim3(256), dim3(256), 0, stream, wqkv, wproj, wt);
  hipLaunchKernelGGL(win_attn, dim3(4096 / NWIN), dim3(TPB), 0, stream,
                     x, bqkv, bproj, wt, (float*)d_out);
}

// Round 17
// 79.330 us; speedup vs baseline: 1.4277x; 1.0769x over previous
//
#include <hip/hip_runtime.h>
#include <hip/hip_bf16.h>

typedef short bf16x8 __attribute__((ext_vector_type(8)));
typedef short bf16x4 __attribute__((ext_vector_type(4)));
typedef float f32x4 __attribute__((ext_vector_type(4)));
typedef unsigned short ushort8v __attribute__((ext_vector_type(8)));

#define TPB  512
#define NWIN 8            // windows per persistent block; grid = 4096/NWIN = 512 = 2/CU exactly

// r15 lesson (== guide m141): barrier asm + "memory" clobber + sched_barrier(0)
// blocked the compiler's loop-invariant load hoisting (VGPR 124->96, dur +37%).
// Keep plain __syncthreads(); instead, make the hoists explicit in source and
// issue prefetches early enough that S3's vmcnt(0) drain finds them complete.

// HW bf16 convert (RNE) — compiler emits v_cvt_pk_bf16_f32; do NOT hand-roll (r7/r8 lesson).
__device__ __forceinline__ unsigned short f2bf(float f) {
  __hip_bfloat16 h = __float2bfloat16(f);
  return __builtin_bit_cast(unsigned short, h);
}

__device__ __forceinline__ bf16x4 pack4(float a, float b, float c, float d) {
  bf16x4 v;
  v[0] = (short)f2bf(a); v[1] = (short)f2bf(b);
  v[2] = (short)f2bf(c); v[3] = (short)f2bf(d);
  return v;
}

// K=16 bf16 MFMA. A-frag k-pattern (k=4g+j) == D-layout row pattern (row=4g+r),
// so D-fragments feed K=16 MFMAs directly; with B = c*Identity it TRANSPOSES a
// 16x16 block in the matrix pipe (D = c*X^T).
__device__ __forceinline__ f32x4 mfma16(bf16x4 a, bf16x4 b, f32x4 c) {
#if __has_builtin(__builtin_amdgcn_mfma_f32_16x16x16_bf16)
  return __builtin_amdgcn_mfma_f32_16x16x16_bf16(a, b, c, 0, 0, 0);
#elif __has_builtin(__builtin_amdgcn_mfma_f32_16x16x16bf16_1k)
  return __builtin_amdgcn_mfma_f32_16x16x16bf16_1k(a, b, c, 0, 0, 0);
#else
  f32x4 d;
  asm("v_mfma_f32_16x16x16_bf16 %0, %1, %2, %3" : "=v"(d) : "v"(a), "v"(b), "v"(c));
  return d;
#endif
}

// raw v_exp_f32 / v_rcp_f32 — skip ocml edge-case wrappers (r12/r13: real VALU win)
__device__ __forceinline__ float exp2_raw(float x) {
#if __has_builtin(__builtin_amdgcn_exp2f)
  return __builtin_amdgcn_exp2f(x);
#else
  float r; asm("v_exp_f32 %0, %1" : "=v"(r) : "v"(x)); return r;
#endif
}
__device__ __forceinline__ float rcp_raw(float x) {
#if __has_builtin(__builtin_amdgcn_rcpf)
  return __builtin_amdgcn_rcpf(x);
#else
  float r; asm("v_rcp_f32 %0, %1" : "=v"(r) : "v"(x)); return r;
#endif
}

// LDS map (ushort elems). Persistent-loop overlays (r14):
//   [0..8192)      sWin (staging, overlays dead Q of previous iteration)
//   [0..10240)     Q    (QKV phase -> bq regs)
//   [10240..20480) K    (QKV phase -> ak regs)
//   [10240..18432) ATT  (overlays dead K — this is what frees the stage-write slot)
//   [20480..29696) VT
#define Q_OFF   0
#define K_OFF   10240
#define ATT_OFF 10240
#define VT_OFF  20480
#define SMEM_ELEMS 29696 // 59,392 B -> 2 blocks/CU (118,784 <= 131,072 usable)

// scale * log2(e): softmax in log2 domain; logits tiny -> no max-subtraction needed.
#define CQ 0.25501817f   // (1/sqrt(32)) * 1.4426950408889634

__global__ void prep_weights(const float* __restrict__ wqkv,
                             const float* __restrict__ wproj,
                             unsigned short* __restrict__ wt) {
  int idx = blockIdx.x * 256 + threadIdx.x;
  if (idx < 384 * 128) {                 // wqkvT[n][k] = bf16(wqkv[k][n])
    int n = idx >> 7, k = idx & 127;
    wt[idx] = f2bf(wqkv[k * 384 + n]);
  } else if (idx < 384 * 128 + 128 * 128) { // wprojT[c][k] = bf16(wproj[k][c])
    int j = idx - 384 * 128;
    int c = j >> 7, k = j & 127;
    wt[idx] = f2bf(wproj[k * 128 + c]);
  }
}

__device__ __forceinline__ size_t winbase_of(int wid) {
  int b = wid >> 8, wh = (wid >> 4) & 15, ww = wid & 15;
  return (((size_t)b * 112 + wh * 7) * 112 + ww * 7) * 128;
}

__launch_bounds__(TPB, 2)   // cap 128 VGPR; residency is LDS-pinned at 2 blocks/CU anyway
__global__ void win_attn(const float* __restrict__ x,
                         const float* __restrict__ bqkv,
                         const float* __restrict__ bproj,
                         const unsigned short* __restrict__ wt,
                         float* __restrict__ out) {
  __shared__ __align__(16) unsigned short smem[SMEM_ELEMS];
  const int tid  = threadIdx.x;
  const int wave = tid >> 6;
  const int lane = tid & 63;
  const int g    = lane >> 4;   // 16-lane group id (0..3)
  const int l15  = lane & 15;

  const unsigned short* wqkvT  = wt;               // [384][128] bf16
  const unsigned short* wprojT = wt + 384 * 128;   // [128][128] bf16

  // identity B-frags for the transpose-mfma: B[k=4g+j][col=l15] = c * delta(4g+j, l15)
  bf16x4 idQ = {0, 0, 0, 0}, idK = {0, 0, 0, 0};
  if ((l15 >> 2) == g) {
    idQ[l15 & 3] = (short)f2bf(CQ);       // Q gets scale*log2e folded in
    idK[l15 & 3] = (short)0x3F80;         // 1.0 bf16
  }

  // staging geometry (invariant): thread covers rows row0 and row0+32; rows>48 clamp
  // to row 48 (finite garbage safe: K toks masked, V toks killed by P=0, Q rows unused).
  // (row+32)&7 == row&7, so both chunks share the same XOR granule.
  const int row0  = tid >> 4, c8 = tid & 15;
  const int rowc0 = min(row0, 48), rowc1 = min(row0 + 32, 48);
  const int xo0   = ((rowc0 / 7) * 112 + (rowc0 % 7)) * 128 + c8 * 8;
  const int xo1   = ((rowc1 / 7) * 112 + (rowc1 % 7)) * 128 + c8 * 8;
  const int sw    = (c8 * 8) ^ ((row0 & 7) << 3);
  const int dst0  = row0 * 128 + sw;
  const int dst1  = (row0 + 32) * 128 + sw;

  const f32x4 zero4 = {0.f, 0.f, 0.f, 0.f};
  const int h    = wave >> 1;
  const int half = wave & 1;
  const int ccol = wave * 16 + l15;

  // proj weights + bias: loop-invariant — hoist ONCE (r15 lesson: make it explicit)
  bf16x8 bwp[4];
#pragma unroll
  for (int kt = 0; kt < 4; kt++)
    bwp[kt] = *(const bf16x8*)(wprojT + ccol * 128 + kt * 32 + g * 8);
  const float biasp = bproj[ccol];

  // ---------- prologue: stage window 0 ----------
  float4 pfa, pfb, pfc, pfd;
  {
    size_t wb0 = winbase_of((int)blockIdx.x);   // w=0: wid = blockIdx.x
    const float4* s0 = (const float4*)(x + wb0 + xo0);
    const float4* s1 = (const float4*)(x + wb0 + xo1);
    pfa = s0[0]; pfb = s0[1]; pfc = s1[0]; pfd = s1[1];
  }
  {
    ushort8v v8;
    v8[0]=f2bf(pfa.x); v8[1]=f2bf(pfa.y); v8[2]=f2bf(pfa.z); v8[3]=f2bf(pfa.w);
    v8[4]=f2bf(pfb.x); v8[5]=f2bf(pfb.y); v8[6]=f2bf(pfb.z); v8[7]=f2bf(pfb.w);
    *(ushort8v*)(&smem[dst0]) = v8;
    v8[0]=f2bf(pfc.x); v8[1]=f2bf(pfc.y); v8[2]=f2bf(pfc.z); v8[3]=f2bf(pfc.w);
    v8[4]=f2bf(pfd.x); v8[5]=f2bf(pfd.y); v8[6]=f2bf(pfd.z); v8[7]=f2bf(pfd.w);
    *(ushort8v*)(&smem[dst1]) = v8;
  }
  __syncthreads();   // S0: sWin(0) visible

  for (int w = 0; w < NWIN; w++) {
    const int wid = w * 512 + (int)blockIdx.x;
    const size_t winbase = winbase_of(wid);

    // ---------- af loads (sWin -> regs) ----------
    bf16x8 af[4][4];
#pragma unroll
    for (int mt = 0; mt < 4; mt++)
#pragma unroll
      for (int kt = 0; kt < 4; kt++) {
        int row = mt * 16 + l15;
        int colE = kt * 32 + g * 8;
        af[mt][kt] = *(const bf16x8*)(&smem[row * 128 + (colE ^ ((row & 7) << 3))]);
      }
    __syncthreads();   // S1: af (and prev-iter proj ATT reads) done; QKV writes safe

    // ---------- phase 1: QKV = win @ w_qkv + b_qkv ----------
#pragma unroll
    for (int i = 0; i < 3; i++) {
      int nt = wave * 3 + i;          // 0..23 (n-tile of 384)
      int n  = nt * 16 + l15;
      float bias = bqkv[n];
      f32x4 binit = {bias, bias, bias, bias};

      bf16x8 bw[4];
#pragma unroll
      for (int kt = 0; kt < 4; kt++)
        bw[kt] = *(const bf16x8*)(wqkvT + n * 128 + kt * 32 + g * 8);

      f32x4 acc[4] = {binit, binit, binit, binit};
      __builtin_amdgcn_s_setprio(1);
#pragma unroll
      for (int kt = 0; kt < 4; kt++)
#pragma unroll
        for (int mt = 0; mt < 4; mt++)
          acc[mt] = __builtin_amdgcn_mfma_f32_16x16x32_bf16(af[mt][kt], bw[kt], acc[mt], 0, 0, 0);
      __builtin_amdgcn_s_setprio(0);

      int sec = nt >> 3;       // 0=Q 1=K 2=V (uniform per (wave,i))
      if (sec == 2) {
        int hn = n & 127, hh = hn >> 5, d = hn & 31;
#pragma unroll
        for (int mt = 0; mt < 4; mt++) {
          bf16x4 pv = pack4(acc[mt][0], acc[mt][1], acc[mt][2], acc[mt][3]);
          *(bf16x4*)(&smem[VT_OFF + hh * 2304 + d * 72 + mt * 16 + g * 4]) = pv;
        }
      } else {
        int t7 = nt & 7;
        int hh = t7 >> 1, d0 = (t7 & 1) * 16;
        const bf16x4 idf = (sec == 0) ? idQ : idK;
        const int base = (sec == 0 ? Q_OFF : K_OFF) + hh * 2560 + d0 + g * 4;
#pragma unroll
        for (int mt = 0; mt < 4; mt++) {
          bf16x4 ax = pack4(acc[mt][0], acc[mt][1], acc[mt][2], acc[mt][3]);
          f32x4 dt = mfma16(ax, idf, zero4);
          bf16x4 wv = pack4(dt[0], dt[1], dt[2], dt[3]);
          *(bf16x4*)(&smem[base + (mt * 16 + l15) * 40]) = wv;
        }
      }
    }
    __syncthreads();   // S2: Q/K/VT visible

    // T14 (moved earlier, r17): issue next window's staging loads NOW — the whole
    // attention phase (~thousands of cycles) covers their latency before S3's
    // vmcnt(0) drain. Live range sits in the attention phase, below the QKV peak.
    if (w < NWIN - 1) {
      size_t wbn = winbase_of(wid + 512);
      const float4* s0 = (const float4*)(x + wbn + xo0);
      const float4* s1 = (const float4*)(x + wbn + xo1);
      pfa = s0[0]; pfb = s0[1]; pfc = s1[0]; pfd = s1[1];
    }

    // ---------- phase 2: attention, swapped QK^T ----------
    bf16x8 ak[4];
#pragma unroll
    for (int kt = 0; kt < 4; kt++) {
      int row = kt * 16 + l15;
      ak[kt] = *(const bf16x8*)(&smem[K_OFF + h * 2560 + row * 40 + g * 8]);
    }
    bf16x8 bq[2];
#pragma unroll
    for (int qt = 0; qt < 2; qt++) {
      int row = half * 32 + qt * 16 + l15;
      bq[qt] = *(const bf16x8*)(&smem[Q_OFF + h * 2560 + row * 40 + g * 8]);
    }
    bf16x4 bv16[2][4];
#pragma unroll
    for (int nt2 = 0; nt2 < 2; nt2++)
#pragma unroll
      for (int kt = 0; kt < 4; kt++)
        bv16[nt2][kt] = *(const bf16x4*)(&smem[VT_OFF + h * 2304 + (nt2 * 16 + l15) * 72 + kt * 16 + g * 4]);

    f32x4 s[4][2];
    __builtin_amdgcn_s_setprio(1);
#pragma unroll
    for (int kt = 0; kt < 4; kt++)
#pragma unroll
      for (int qt = 0; qt < 2; qt++)
        s[kt][qt] = __builtin_amdgcn_mfma_f32_16x16x32_bf16(ak[kt], bq[qt], zero4, 0, 0, 0);
    __builtin_amdgcn_s_setprio(0);

    // softmax (no max-subtraction; only tok 48 of kt=3 is valid)
    bf16x4 ap16[2][4];
    const bool v48 = (g == 0);
#pragma unroll
    for (int qt = 0; qt < 2; qt++) {
      float sum = 0.f;
#pragma unroll
      for (int kt = 0; kt < 3; kt++)
#pragma unroll
        for (int r = 0; r < 4; r++) {
          float p = exp2_raw(s[kt][qt][r]);
          s[kt][qt][r] = p;
          sum += p;
        }
      float p3 = v48 ? exp2_raw(s[3][qt][0]) : 0.0f;
      sum += p3;
      sum += __shfl_xor(sum, 16);
      sum += __shfl_xor(sum, 32);
      float inv = rcp_raw(sum);
#pragma unroll
      for (int kt = 0; kt < 3; kt++)
        ap16[qt][kt] = pack4(s[kt][qt][0] * inv, s[kt][qt][1] * inv,
                             s[kt][qt][2] * inv, s[kt][qt][3] * inv);
      ap16[qt][3] = pack4(p3 * inv, 0.f, 0.f, 0.f);
    }

    // PV straight from registers
    f32x4 o[2][2] = {{zero4, zero4}, {zero4, zero4}};
    __builtin_amdgcn_s_setprio(1);
#pragma unroll
    for (int kt = 0; kt < 4; kt++)
#pragma unroll
      for (int m2 = 0; m2 < 2; m2++)
#pragma unroll
        for (int nt2 = 0; nt2 < 2; nt2++)
          o[m2][nt2] = mfma16(ap16[m2][kt], bv16[nt2][kt], o[m2][nt2]);
    __builtin_amdgcn_s_setprio(0);

    // transpose O tiles in the matrix pipe (reg-only)
    bf16x4 attw[2][2];
#pragma unroll
    for (int m2 = 0; m2 < 2; m2++)
#pragma unroll
      for (int nt2 = 0; nt2 < 2; nt2++) {
        bf16x4 ox = pack4(o[m2][nt2][0], o[m2][nt2][1], o[m2][nt2][2], o[m2][nt2][3]);
        f32x4 ot = mfma16(ox, idK, zero4);
        attw[m2][nt2] = pack4(ot[0], ot[1], ot[2], ot[3]);
      }

    __syncthreads();   // S3: all Q/K/VT reads done; ATT (over K) + sWin (over Q) writable

#pragma unroll
    for (int m2 = 0; m2 < 2; m2++)
#pragma unroll
      for (int nt2 = 0; nt2 < 2; nt2++) {
        int tok  = (half * 2 + m2) * 16 + l15;
        int col0 = h * 32 + nt2 * 16 + g * 4;
        *(bf16x4*)(&smem[ATT_OFF + tok * 128 + (col0 ^ ((tok & 7) << 3))]) = attw[m2][nt2];
      }
    if (w < NWIN - 1) {
      ushort8v v8;
      v8[0]=f2bf(pfa.x); v8[1]=f2bf(pfa.y); v8[2]=f2bf(pfa.z); v8[3]=f2bf(pfa.w);
      v8[4]=f2bf(pfb.x); v8[5]=f2bf(pfb.y); v8[6]=f2bf(pfb.z); v8[7]=f2bf(pfb.w);
      *(ushort8v*)(&smem[dst0]) = v8;
      v8[0]=f2bf(pfc.x); v8[1]=f2bf(pfc.y); v8[2]=f2bf(pfc.z); v8[3]=f2bf(pfc.w);
      v8[4]=f2bf(pfd.x); v8[5]=f2bf(pfd.y); v8[6]=f2bf(pfd.z); v8[7]=f2bf(pfd.w);
      *(ushort8v*)(&smem[dst1]) = v8;
    }
    __syncthreads();   // S4: ATT + next sWin visible

    // ---------- proj + bias + store (fp32 out, nontemporal: out is write-once,
    // keep it from evicting x in L3 — x L3-hit-rate governs prefetch latency) ----------
    f32x4 po[4] = {zero4, zero4, zero4, zero4};
    __builtin_amdgcn_s_setprio(1);
#pragma unroll
    for (int kt = 0; kt < 4; kt++) {
#pragma unroll
      for (int mt = 0; mt < 4; mt++) {
        int row = mt * 16 + l15;
        int colE = kt * 32 + g * 8;
        bf16x8 aa = *(const bf16x8*)(&smem[ATT_OFF + row * 128 + (colE ^ ((row & 7) << 3))]);
        po[mt] = __builtin_amdgcn_mfma_f32_16x16x32_bf16(aa, bwp[kt], po[mt], 0, 0, 0);
      }
    }
    __builtin_amdgcn_s_setprio(0);
#pragma unroll
    for (int mt = 0; mt < 3; mt++)
#pragma unroll
      for (int r = 0; r < 4; r++) {
        int tok = mt * 16 + g * 4 + r;
        size_t off = winbase + ((size_t)(tok / 7) * 112 + (tok % 7)) * 128 + ccol;
        __builtin_nontemporal_store(po[mt][r] + biasp, &out[off]);
      }
    if (g == 0) {
      size_t off = winbase + ((size_t)6 * 112 + 6) * 128 + ccol;   // tok 48 = (6,6)
      __builtin_nontemporal_store(po[3][0] + biasp, &out[off]);
    }
  }
}

extern "C" void kernel_launch(void* const* d_in, const int* in_sizes, int n_in,
                              void* d_out, int out_size, void* d_ws, size_t ws_size,
                              hipStream_t stream) {
  (void)in_sizes; (void)n_in; (void)out_size; (void)ws_size;
  const float* x     = (const float*)d_in[0];
  const float* wqkv  = (const float*)d_in[1];
  const float* bqkv  = (const float*)d_in[2];
  const float* wproj = (const float*)d_in[3];
  const float* bproj = (const float*)d_in[4];
  unsigned short* wt = (unsigned short*)d_ws;   // 131072 B: wqkvT + wprojT (bf16)

  hipLaunchKernelGGL(prep_weights, dim3(256), dim3(256), 0, stream, wqkv, wproj, wt);
  hipLaunchKernelGGL(win_attn, dim3(4096 / NWIN), dim3(TPB), 0, stream,
                     x, bqkv, bproj, wt, (float*)d_out);
}